// Round 9
// baseline (36.020 us; speedup 1.0000x reference)
//
#include <hip/hip_runtime.h>
#include <hip/hip_fp16.h>

#define BATCH 8192
#define IN_F 128
#define OUT_F 256
#define LC 23        // grid_size + order
#define NKB 80       // flat K-blocks: 128 j * 20 slots / 32
#define KBPW 10      // K-blocks per wave (8-way split)

typedef _Float16 f16x8 __attribute__((ext_vector_type(8)));
typedef float f32x4 __attribute__((ext_vector_type(4)));
typedef _Float16 half2v __attribute__((ext_vector_type(2)));

// ===========================================================================
// prep_kernel9: coeffs[O][I][23] f32 -> cp3 flat-K f16 B-fragments (1.25 MiB).
// Flat K axis: slot f = j*20 + s (s in [0,20)), total 2560 = 80 kb x 32.
// cp3[kb][g][lane=(q,col)][8 f16]: element e = flat slot kb*32+q*8+e of
// output col i = g*16+col.  Exactly the 16x16x32 B-frag register layout.
// ===========================================================================
__global__ __launch_bounds__(256) void prep_kernel9(
    const float* __restrict__ coeffs, char* __restrict__ cp3) {
    int t = blockIdx.x * 256 + threadIdx.x;   // [0,81920) = [kb][g][q][col]
    int col = t & 15;
    int q = (t >> 4) & 3;
    int g = (t >> 6) & 15;
    int kb = t >> 10;
    int i = g * 16 + col;
    int fbase = kb * 32 + q * 8;
    f16x8 w;
#pragma unroll
    for (int e = 0; e < 8; ++e) {
        int f = fbase + e;
        int j = f / 20;          // magic-mul div (compile-time const)
        int s = f - 20 * j;
        w[e] = (_Float16)coeffs[((size_t)i * IN_F + j) * LC + s];
    }
    *reinterpret_cast<f16x8*>(cp3 + (size_t)t * 16) = w;
}

// ===========================================================================
// kan_mfma9: out = W * C via mfma_f32_16x16x32_f16 over flat K=2560.
// Block: 512 thr = 8 INDEPENDENT waves; wave ks owns kb in [ks*10,ks*10+10).
// Block tile 64x64 (bn in [0,4)); wave computes full 64x64 partial (4mf x
// 4nf, acc=64 VGPR).  Grid = 128 mb x 4 bn = 512 -> 2 blocks/CU, 16 waves/CU.
// Phase 0: meta {lo, hi | (p<<16)}, p = j*10 + (k>>1) GLOBAL pair index.
// K-loop: ping-pong B prefetch; A-frag per (mf,kb) built by chained selects
// over the <=3 j's whose pairs intersect the kb's 16-pair window
// (increasing-j order; cross-j hi collision only when hi==0 -> safe).
// Epilogue: 8-partial LDS reduce in 2 half-passes (R8-verified).
// ===========================================================================
__global__ __launch_bounds__(512, 4) void kan_mfma9(
    const float* __restrict__ x, const char* __restrict__ cp3,
    float* __restrict__ out) {
    __shared__ uint2 mlds[IN_F][64];   // 64 KiB: [j][row] meta

    const int tid = threadIdx.x;
    const int lane = tid & 63;
    const int ks = tid >> 6;           // wave id [0,8)
    const int l15 = lane & 15;
    const int q = lane >> 4;
    const int q4 = q * 4;

    // bijective XCD swizzle (512 = 8 * 64)
    int wg = (blockIdx.x & 7) * 64 + (blockIdx.x >> 3);
    const int mb = wg >> 2;   // [0,128)
    const int bn = wg & 3;    // [0,4)
    const int b0 = mb * 64;

    // ---- Phase 0: meta for 64 rows x 128 j -> LDS ----
    {
        const int row = lane;
        const int jb = ks * 16;
        const float4* xr = reinterpret_cast<const float4*>(
            x + (size_t)(b0 + row) * IN_F + jb);
#pragma unroll
        for (int u = 0; u < 4; ++u) {
            float4 xv = xr[u];
#pragma unroll
            for (int e = 0; e < 4; ++e) {
                float xvv = (e == 0) ? xv.x : (e == 1) ? xv.y
                           : (e == 2) ? xv.z : xv.w;
                float s = 1.0f / (1.0f + __expf(-xvv));
                float idxf = s * 19.0f;
                int k = (int)idxf;            // floor (idxf >= 0)
                k = (k > 18) ? 18 : k;
                float w1 = idxf - (float)k;
                float w0 = 1.0f - w1;
                unsigned u0 = __half_as_ushort(__float2half(w0));
                unsigned u1 = __half_as_ushort(__float2half(w1));
                unsigned lo, hi;
                if (k & 1) { lo = u0 << 16; hi = u1; }
                else       { lo = u0 | (u1 << 16); hi = 0u; }
                int j = jb + u * 4 + e;
                unsigned p = (unsigned)(j * 10 + (k >> 1));  // global pair
                mlds[j][row] = uint2{lo, hi | (p << 16)};
            }
        }
    }
    __syncthreads();

    // ---- K-loop over 10 kb ----
    const int kb0 = ks * KBPW;
    const char* bbase = cp3 + lane * 16;
    auto bld = [&](int kb, int nf) {
        return *reinterpret_cast<const f16x8*>(
            bbase + ((size_t)((kb * 16 + bn * 4 + nf)) << 10));
    };

    f32x4 acc[4][4];
#pragma unroll
    for (int mf = 0; mf < 4; ++mf)
#pragma unroll
        for (int nf = 0; nf < 4; ++nf) acc[mf][nf] = f32x4{0.f, 0.f, 0.f, 0.f};

    f16x8 rc[4], rn[4];
#pragma unroll
    for (int h = 0; h < 4; ++h) rc[h] = bld(kb0, h);

    auto step = [&](f16x8 (&cur)[4], f16x8 (&nxt)[4], int kb, int kbn) {
        // prefetch next kb's B-frags (land under A-build + MFMA)
#pragma unroll
        for (int h = 0; h < 4; ++h) nxt[h] = bld(kbn, h);
        const int pwin = kb * 16;          // window base pair
        const int base = pwin + q4;        // this quadrant's first pair
        const int j0 = pwin / 10;
        const int jB = (j0 + 1 < IN_F - 1) ? j0 + 1 : IN_F - 1;
        const int jC = (j0 + 2 < IN_F - 1) ? j0 + 2 : IN_F - 1;
#pragma unroll
        for (int mf = 0; mf < 4; ++mf) {
            const int row = mf * 16 + l15;
            uint2 m0 = mlds[j0][row];
            uint2 m1 = mlds[jB][row];
            uint2 m2 = mlds[jC][row];
            int d0 = (int)(m0.y >> 16) - base;
            int d1 = (int)(m1.y >> 16) - base;
            int d2 = (int)(m2.y >> 16) - base;
            unsigned h0 = m0.y & 0xFFFFu, h1 = m1.y & 0xFFFFu,
                     h2 = m2.y & 0xFFFFu;
            union { uint32_t u[4]; f16x8 h; } au;
#pragma unroll
            for (int r = 0; r < 4; ++r) {
                uint32_t v = 0u;
                v = (d0 == r) ? m0.x : v;
                v = (d0 == r - 1) ? h0 : v;
                v = (d1 == r) ? m1.x : v;       // increasing-j order:
                v = (d1 == r - 1) ? h1 : v;     // real lo overwrites hi==0
                v = (d2 == r) ? m2.x : v;
                v = (d2 == r - 1) ? h2 : v;
                au.u[r] = v;
            }
#pragma unroll
            for (int nf = 0; nf < 4; ++nf)
                acc[mf][nf] = __builtin_amdgcn_mfma_f32_16x16x32_f16(
                    au.h, cur[nf], acc[mf][nf], 0, 0, 0);
        }
    };

    for (int kk = 0; kk < KBPW; kk += 2) {
        step(rc, rn, kb0 + kk, kb0 + kk + 1);
        int kwrap = (kk + 2 < KBPW) ? (kb0 + kk + 2) : kb0;   // wrap: no br
        step(rn, rc, kb0 + kk + 1, kwrap);
    }

    // ---- Epilogue: reduce 8 wave-partials in 2 column-half passes ----
    __syncthreads();   // all waves done reading mlds
    float* red = reinterpret_cast<float*>(&mlds[0][0]);   // 16384 f32
#pragma unroll
    for (int p = 0; p < 2; ++p) {
        if (p) __syncthreads();
        // C/D layout col=l15, row=q4+r (R3..R8-verified); XOR-16 swizzle
#pragma unroll
        for (int mf = 0; mf < 4; ++mf)
#pragma unroll
            for (int t = 0; t < 2; ++t)
#pragma unroll
                for (int r = 0; r < 4; ++r) {
                    int colsw = (t * 16 + l15 + (q & 1) * 16) & 31;
                    red[ks * 2048 + (mf * 16 + q4 + r) * 32 + colsw] =
                        acc[mf][p * 2 + t][r];
                }
        __syncthreads();
#pragma unroll
        for (int it = 0; it < 4; ++it) {
            int idx = it * 512 + tid;   // [0,2048) = [64 rows][32 cols]
            int row = idx >> 5;
            int col = idx & 31;
            int colsw = (col + ((row >> 2) & 1) * 16) & 31;
            float s = 0.f;
#pragma unroll
            for (int w = 0; w < 8; ++w) s += red[w * 2048 + row * 32 + colsw];
            out[(size_t)(b0 + row) * OUT_F + bn * 64 + p * 32 + col] = s;
        }
    }
}

// ===========================================================================
// Fallback paths (R2-validated) — used only if d_ws is too small.
// ===========================================================================
__device__ __forceinline__ float dot2_acc(unsigned cbits, unsigned wbits,
                                          float acc) {
#if __has_builtin(__builtin_amdgcn_fdot2)
    union { unsigned u; half2v h; } c, w;
    c.u = cbits; w.u = wbits;
    return __builtin_amdgcn_fdot2(c.h, w.h, acc, false);
#else
    __half2 hc = *reinterpret_cast<const __half2*>(&cbits);
    __half2 hw = *reinterpret_cast<const __half2*>(&wbits);
    float2 fc = __half22float2(hc);
    float2 fw = __half22float2(hw);
    return acc + fc.x * fw.x + fc.y * fw.y;
#endif
}

__global__ __launch_bounds__(256) void build_ctg_kernel(
    const float* __restrict__ coeffs, unsigned short* __restrict__ ctg) {
    int tid = blockIdx.x * 256 + threadIdx.x;
    int qq = tid & 63;
    int k = (tid >> 6) % LC;
    int j = tid / (64 * LC);
    if (j >= IN_F) return;
    int k1 = (k + 1 < LC) ? (k + 1) : (LC - 1);
    union { unsigned short h[8]; uint4 v; } u;
#pragma unroll
    for (int c = 0; c < 4; ++c) {
        int i = qq * 4 + c;
        const float* base = coeffs + ((size_t)i * IN_F + j) * LC;
        u.h[2 * c]     = __half_as_ushort(__float2half(base[k]));
        u.h[2 * c + 1] = __half_as_ushort(__float2half(base[k1]));
    }
    reinterpret_cast<uint4*>(ctg)[tid] = u.v;
}

__global__ __launch_bounds__(256) void kan_main_kernel(
    const float* __restrict__ x, const char* __restrict__ ctg,
    float* __restrict__ out) {
    __shared__ unsigned metas[4][2 * IN_F];
    const int wave = threadIdx.x >> 6;
    const int lane = threadIdx.x & 63;
    const int b = blockIdx.x * 4 + wave;
    float2 xv = reinterpret_cast<const float2*>(x + (size_t)b * IN_F)[lane];
    uint4 m;
#pragma unroll
    for (int t = 0; t < 2; ++t) {
        float xs = t ? xv.y : xv.x;
        float s = 1.0f / (1.0f + __expf(-xs));
        float idxf = s * 19.0f;
        int k = (int)idxf;
        k = (k > 18) ? 18 : k;
        float w1 = idxf - (float)k;
        float w0 = 1.0f - w1;
        int j = 2 * lane + t;
        unsigned off = (unsigned)((j * LC + k) << 10);
        half2v w; w[0] = (_Float16)w0; w[1] = (_Float16)w1;
        unsigned wbits = *reinterpret_cast<unsigned*>(&w);
        if (t == 0) { m.x = off; m.y = wbits; }
        else        { m.z = off; m.w = wbits; }
    }
    reinterpret_cast<uint4*>(&metas[wave][0])[lane] = m;
    __syncthreads();
    const unsigned lanebase = lane * 16;
    const uint4* mrow = reinterpret_cast<const uint4*>(&metas[wave][0]);
    float acc0 = 0.f, acc1 = 0.f, acc2 = 0.f, acc3 = 0.f;
#pragma unroll 8
    for (int j2 = 0; j2 < IN_F / 2; ++j2) {
        uint4 mm = mrow[j2];
        {
            const uint4 e = *reinterpret_cast<const uint4*>(
                ctg + (size_t)(lanebase + mm.x));
            acc0 = dot2_acc(e.x, mm.y, acc0);
            acc1 = dot2_acc(e.y, mm.y, acc1);
            acc2 = dot2_acc(e.z, mm.y, acc2);
            acc3 = dot2_acc(e.w, mm.y, acc3);
        }
        {
            const uint4 e = *reinterpret_cast<const uint4*>(
                ctg + (size_t)(lanebase + mm.z));
            acc0 = dot2_acc(e.x, mm.w, acc0);
            acc1 = dot2_acc(e.y, mm.w, acc1);
            acc2 = dot2_acc(e.z, mm.w, acc2);
            acc3 = dot2_acc(e.w, mm.w, acc3);
        }
    }
    float4 r = make_float4(acc0, acc1, acc2, acc3);
    reinterpret_cast<float4*>(out + (size_t)b * OUT_F)[lane] = r;
}

// ===========================================================================
extern "C" void kernel_launch(void* const* d_in, const int* in_sizes, int n_in,
                              void* d_out, int out_size, void* d_ws,
                              size_t ws_size, hipStream_t stream) {
    const float* x = (const float*)d_in[0];       // [8192, 128] f32
    const float* coeffs = (const float*)d_in[1];  // [256, 128, 23] f32
    float* out = (float*)d_out;                   // [8192, 256] f32

    const size_t cp3_bytes = (size_t)NKB * 16 * 64 * 16;   // 1.25 MiB
    const size_t ctg_bytes = (size_t)IN_F * LC * 64 * 16;  // ~2.9 MiB

    if (d_ws != nullptr && ws_size >= cp3_bytes) {
        char* cp3 = (char*)d_ws;
        prep_kernel9<<<320, 256, 0, stream>>>(coeffs, cp3);
        kan_mfma9<<<512, 512, 0, stream>>>(x, cp3, out);
    } else if (d_ws != nullptr && ws_size >= ctg_bytes) {
        char* ctg = (char*)d_ws;
        const int totalA = IN_F * LC * 64;
        build_ctg_kernel<<<(totalA + 255) / 256, 256, 0, stream>>>(
            coeffs, (unsigned short*)ctg);
        kan_main_kernel<<<BATCH / 4, 256, 0, stream>>>(x, ctg, out);
    } else {
        kan_main_kernel<<<BATCH / 4, 256, 0, stream>>>(x, (const char*)d_ws,
                                                       out);
    }
}

// Round 10
// 32.473 us; speedup vs baseline: 1.1092x; 1.1092x over previous
//
#include <hip/hip_runtime.h>
#include <hip/hip_fp16.h>

#define BATCH 8192
#define IN_F 128
#define OUT_F 256
#define LC 23        // grid_size + order
#define BROW 768     // bytes per (j,g) cp2 row: 16 cols x 24 slots x 2B
#define JPW 32       // j's per wave (4-way in-block K-split)

typedef _Float16 f16x8 __attribute__((ext_vector_type(8)));
typedef float f32x4 __attribute__((ext_vector_type(4)));
typedef _Float16 half2v __attribute__((ext_vector_type(2)));

// ===========================================================================
// prep_kernel: repack coeffs -> cp2 (f16 B-fragments, 24-slot rows, 1.5 MiB).
//   cp2 row (j,g): [q 3][col 16][16B]; (q,col) holds slots 8q..8q+7 of
//   output col i=g*16+col (slot >= 20 -> 0).  16x16x32 B-frag register
//   layout for lane quadrants q<3; q=3 frag unused (A there is zero).
//   (R5..R8-verified)
// ===========================================================================
__global__ __launch_bounds__(256) void prep_kernel(
    const float* __restrict__ coeffs, _Float16* __restrict__ cp2) {
    int t = blockIdx.x * 256 + threadIdx.x;   // [0, 98304)
    int col = t & 15;
    int u = t >> 4;          // [0, 6144)
    int q = u % 3;
    int v = u / 3;           // [0, 2048)
    int g = v & 15;
    int j = v >> 4;          // [0, 128)
    int i = g * 16 + col;
    int s0 = q * 8;
    const float* src = coeffs + ((size_t)i * IN_F + j) * LC;
    f16x8 w;
#pragma unroll
    for (int e = 0; e < 8; ++e) {
        int s = s0 + e;
        float f = (s < 20) ? src[s] : 0.0f;
        w[e] = (_Float16)f;
    }
    char* dst = reinterpret_cast<char*>(cp2) +
                (size_t)(j * 16 + g) * BROW + q * 256 + col * 16;
    *reinterpret_cast<f16x8*>(dst) = w;
}

// ===========================================================================
// kan_mfma10: out = W * C via mfma_f32_16x16x32_f16.
// Register-budget-first reshape of R8:
//   Block: 512 thr = 8 waves = 2 M-halves (mh) x 4 K-split (ks).
//   Wave tile 32 x 64 (mf=2 x nf=4, acc = 32 VGPR); wave owns 32 j.
//   Grid = 128 mb x 4 bn = 512 -> 2 blocks/CU (LDS 64 KB), 4 waves/SIMD,
//   and ~120 VGPR fits __launch_bounds__(512,4) WITHOUT spills.
// K-loop: 2-DEEP prefetch via 4 named B-buffers (B0..B3, 64 VGPR),
//   unroll-4, wrap-indexed loads (no branches).  q=3 lanes re-read q=2
//   bytes (A-frag there is structurally zero; HW merges duplicate addrs).
// Phase 0: meta {lo, hi | (P<<16)}, P = k>>1 -> 64 KiB LDS (R7/R8-verified).
// Epilogue: single-pass 8-partial reduce (exactly 64 KiB), q-swizzled
//   columns -> conflict-free writes and reads.
// ===========================================================================
__global__ __launch_bounds__(512, 4) void kan_mfma10(
    const float* __restrict__ x, const char* __restrict__ cp2,
    float* __restrict__ out) {
    __shared__ uint2 mlds[IN_F][64];   // 64 KiB: [j][row] meta

    const int tid = threadIdx.x;
    const int lane = tid & 63;
    const int wave = tid >> 6;
    const int ks = wave & 3;           // K-split id [0,4)
    const int mh = wave >> 2;          // M-half [0,2)
    const int l15 = lane & 15;
    const int q = lane >> 4;
    const int q4 = q * 4;
    const int qc = (q < 3) ? q : 2;    // q=3 reads q=2's bytes (A=0 there)

    // bijective XCD swizzle (512 = 8 * 64)
    int wg = (blockIdx.x & 7) * 64 + (blockIdx.x >> 3);
    const int mb = wg >> 2;   // [0,128)
    const int bn = wg & 3;    // [0,4)
    const int b0 = mb * 64;

    // ---- Phase 0: meta for 64 rows x 128 j -> LDS ----
    {
        const int row = lane;
        const int jb = wave * 16;
        const float4* xr = reinterpret_cast<const float4*>(
            x + (size_t)(b0 + row) * IN_F + jb);
#pragma unroll
        for (int u = 0; u < 4; ++u) {
            float4 xv = xr[u];
#pragma unroll
            for (int e = 0; e < 4; ++e) {
                float xvv = (e == 0) ? xv.x : (e == 1) ? xv.y
                           : (e == 2) ? xv.z : xv.w;
                float s = 1.0f / (1.0f + __expf(-xvv));
                float idxf = s * 19.0f;
                int k = (int)idxf;            // floor (idxf >= 0)
                k = (k > 18) ? 18 : k;
                float w1 = idxf - (float)k;
                float w0 = 1.0f - w1;
                unsigned u0 = __half_as_ushort(__float2half(w0));
                unsigned u1 = __half_as_ushort(__float2half(w1));
                unsigned lo, hi;
                if (k & 1) { lo = u0 << 16; hi = u1; }
                else       { lo = u0 | (u1 << 16); hi = 0u; }
                unsigned P = (unsigned)(k >> 1);
                mlds[jb + u * 4 + e][row] = uint2{lo, hi | (P << 16)};
            }
        }
    }
    __syncthreads();

    // ---- K-loop: 32 j per wave, 2-deep prefetch, 4 named buffers ----
    const int j0 = ks * JPW;
    const char* bbase = cp2 + (size_t)(bn * 4) * BROW + qc * 256 + l15 * 16;

    f32x4 acc[2][4];
#pragma unroll
    for (int mf = 0; mf < 2; ++mf)
#pragma unroll
        for (int nf = 0; nf < 4; ++nf) acc[mf][nf] = f32x4{0.f, 0.f, 0.f, 0.f};

    f16x8 B0[4], B1[4], B2[4], B3[4];

    auto LOADJ = [&](f16x8 (&buf)[4], int jrel) {
        const char* src = bbase + (size_t)((j0 + (jrel & (JPW - 1))) * 16) * BROW;
#pragma unroll
        for (int nf = 0; nf < 4; ++nf)
            buf[nf] = *reinterpret_cast<const f16x8*>(src + nf * BROW);
    };
    auto STEP = [&](f16x8 (&cur)[4], f16x8 (&tgt)[4], int jc, int jl) {
        LOADJ(tgt, jl);                     // issue loads first (2-deep cover)
        const int j = j0 + jc;
#pragma unroll
        for (int mf = 0; mf < 2; ++mf) {
            uint2 m = mlds[j][mh * 32 + mf * 16 + l15];
            unsigned lo = m.x;
            unsigned hi = m.y & 0xFFFFu;
            int d = (int)(m.y >> 16) - q4;
            union { uint32_t u[4]; f16x8 h; } au;
#pragma unroll
            for (int r = 0; r < 4; ++r) {
                uint32_t v = (d == r) ? lo : 0u;
                v = (d == r - 1) ? hi : v;
                au.u[r] = v;
            }
#pragma unroll
            for (int nf = 0; nf < 4; ++nf)
                acc[mf][nf] = __builtin_amdgcn_mfma_f32_16x16x32_f16(
                    au.h, cur[nf], acc[mf][nf], 0, 0, 0);
        }
    };

    LOADJ(B0, 0);
    LOADJ(B1, 1);
    for (int jj = 0; jj < JPW; jj += 4) {
        STEP(B0, B2, jj + 0, jj + 2);
        STEP(B1, B3, jj + 1, jj + 3);
        STEP(B2, B0, jj + 2, jj + 4);   // jl wraps mod 32 at the tail
        STEP(B3, B1, jj + 3, jj + 5);   // (redundant loads, harmless)
    }

    // ---- Epilogue: single-pass reduce of 8 partials (exactly 64 KiB) ----
    __syncthreads();   // all waves done reading mlds
    float* red = reinterpret_cast<float*>(&mlds[0][0]);   // 16384 f32
    // wave writes its 32x64 partial; col swizzled by writer q -> no conflict
#pragma unroll
    for (int mf = 0; mf < 2; ++mf)
#pragma unroll
        for (int nf = 0; nf < 4; ++nf)
#pragma unroll
            for (int r = 0; r < 4; ++r) {
                int row32 = mf * 16 + q4 + r;
                int colsw = (nf * 16 + l15 + q * 16) & 63;
                red[(wave * 32 + row32) * 64 + colsw] = acc[mf][nf][r];
            }
    __syncthreads();
    // out(row64, col) = sum over ks of partials; mh = row64>>5
#pragma unroll
    for (int it = 0; it < 8; ++it) {
        int idx = it * 512 + tid;       // [0,4096) = [row64][col]
        int row64 = idx >> 6;
        int col = idx & 63;
        int mhh = row64 >> 5;
        int row32 = row64 & 31;
        int colsw = (col + ((row32 >> 2) & 3) * 16) & 63;
        float s = 0.f;
#pragma unroll
        for (int k = 0; k < 4; ++k)
            s += red[((mhh * 4 + k) * 32 + row32) * 64 + colsw];
        out[(size_t)(b0 + row64) * OUT_F + bn * 64 + col] = s;
    }
}

// ===========================================================================
// Fallback paths (R2-validated) — used only if d_ws is too small.
// ===========================================================================
__device__ __forceinline__ float dot2_acc(unsigned cbits, unsigned wbits,
                                          float acc) {
#if __has_builtin(__builtin_amdgcn_fdot2)
    union { unsigned u; half2v h; } c, w;
    c.u = cbits; w.u = wbits;
    return __builtin_amdgcn_fdot2(c.h, w.h, acc, false);
#else
    __half2 hc = *reinterpret_cast<const __half2*>(&cbits);
    __half2 hw = *reinterpret_cast<const __half2*>(&wbits);
    float2 fc = __half22float2(hc);
    float2 fw = __half22float2(hw);
    return acc + fc.x * fw.x + fc.y * fw.y;
#endif
}

__global__ __launch_bounds__(256) void build_ctg_kernel(
    const float* __restrict__ coeffs, unsigned short* __restrict__ ctg) {
    int tid = blockIdx.x * 256 + threadIdx.x;
    int qq = tid & 63;
    int k = (tid >> 6) % LC;
    int j = tid / (64 * LC);
    if (j >= IN_F) return;
    int k1 = (k + 1 < LC) ? (k + 1) : (LC - 1);
    union { unsigned short h[8]; uint4 v; } u;
#pragma unroll
    for (int c = 0; c < 4; ++c) {
        int i = qq * 4 + c;
        const float* base = coeffs + ((size_t)i * IN_F + j) * LC;
        u.h[2 * c]     = __half_as_ushort(__float2half(base[k]));
        u.h[2 * c + 1] = __half_as_ushort(__float2half(base[k1]));
    }
    reinterpret_cast<uint4*>(ctg)[tid] = u.v;
}

__global__ __launch_bounds__(256) void kan_main_kernel(
    const float* __restrict__ x, const char* __restrict__ ctg,
    float* __restrict__ out) {
    __shared__ unsigned metas[4][2 * IN_F];
    const int wave = threadIdx.x >> 6;
    const int lane = threadIdx.x & 63;
    const int b = blockIdx.x * 4 + wave;
    float2 xv = reinterpret_cast<const float2*>(x + (size_t)b * IN_F)[lane];
    uint4 m;
#pragma unroll
    for (int t = 0; t < 2; ++t) {
        float xs = t ? xv.y : xv.x;
        float s = 1.0f / (1.0f + __expf(-xs));
        float idxf = s * 19.0f;
        int k = (int)idxf;
        k = (k > 18) ? 18 : k;
        float w1 = idxf - (float)k;
        float w0 = 1.0f - w1;
        int j = 2 * lane + t;
        unsigned off = (unsigned)((j * LC + k) << 10);
        half2v w; w[0] = (_Float16)w0; w[1] = (_Float16)w1;
        unsigned wbits = *reinterpret_cast<unsigned*>(&w);
        if (t == 0) { m.x = off; m.y = wbits; }
        else        { m.z = off; m.w = wbits; }
    }
    reinterpret_cast<uint4*>(&metas[wave][0])[lane] = m;
    __syncthreads();
    const unsigned lanebase = lane * 16;
    const uint4* mrow = reinterpret_cast<const uint4*>(&metas[wave][0]);
    float acc0 = 0.f, acc1 = 0.f, acc2 = 0.f, acc3 = 0.f;
#pragma unroll 8
    for (int j2 = 0; j2 < IN_F / 2; ++j2) {
        uint4 mm = mrow[j2];
        {
            const uint4 e = *reinterpret_cast<const uint4*>(
                ctg + (size_t)(lanebase + mm.x));
            acc0 = dot2_acc(e.x, mm.y, acc0);
            acc1 = dot2_acc(e.y, mm.y, acc1);
            acc2 = dot2_acc(e.z, mm.y, acc2);
            acc3 = dot2_acc(e.w, mm.y, acc3);
        }
        {
            const uint4 e = *reinterpret_cast<const uint4*>(
                ctg + (size_t)(lanebase + mm.z));
            acc0 = dot2_acc(e.x, mm.w, acc0);
            acc1 = dot2_acc(e.y, mm.w, acc1);
            acc2 = dot2_acc(e.z, mm.w, acc2);
            acc3 = dot2_acc(e.w, mm.w, acc3);
        }
    }
    float4 r = make_float4(acc0, acc1, acc2, acc3);
    reinterpret_cast<float4*>(out + (size_t)b * OUT_F)[lane] = r;
}

// ===========================================================================
extern "C" void kernel_launch(void* const* d_in, const int* in_sizes, int n_in,
                              void* d_out, int out_size, void* d_ws,
                              size_t ws_size, hipStream_t stream) {
    const float* x = (const float*)d_in[0];       // [8192, 128] f32
    const float* coeffs = (const float*)d_in[1];  // [256, 128, 23] f32
    float* out = (float*)d_out;                   // [8192, 256] f32

    const size_t cp2_bytes = (size_t)IN_F * 16 * BROW;           // 1.5 MiB
    const size_t ctg_bytes = (size_t)IN_F * LC * 64 * 16;        // ~2.9 MiB

    if (d_ws != nullptr && ws_size >= cp2_bytes) {
        _Float16* cp2 = (_Float16*)d_ws;
        prep_kernel<<<384, 256, 0, stream>>>(coeffs, cp2);
        kan_mfma10<<<512, 512, 0, stream>>>(x, (const char*)cp2, out);
    } else if (d_ws != nullptr && ws_size >= ctg_bytes) {
        char* ctg = (char*)d_ws;
        const int totalA = IN_F * LC * 64;
        build_ctg_kernel<<<(totalA + 255) / 256, 256, 0, stream>>>(
            coeffs, (unsigned short*)ctg);
        kan_main_kernel<<<BATCH / 4, 256, 0, stream>>>(x, ctg, out);
    } else {
        kan_main_kernel<<<BATCH / 4, 256, 0, stream>>>(x, (const char*)d_ws,
                                                       out);
    }
}